// Round 10
// baseline (243.610 us; speedup 1.0000x reference)
//
#include <hip/hip_runtime.h>
#include <hip/hip_bf16.h>

#define BATCH   2
#define SEQ     2048
#define DMODEL  1024
#define DINNER  2048
#define DSTATE  64
#define NHEADS  32
#define HEADDIM 64
#define CONVDIM 2176
#define DINPROJ 4256
#define NPAD    4352        // DINPROJ padded to 34*128 for the MFMA GEMM
#define NCHUNK  32          // SEQ / 64
#define EPSF    1e-5f
#define SP      88          // LDS row stride (bf16) for SSD kernels
#define NG      276         // (CONVDIM + NHEADS) / 8 channel-groups per row

typedef __bf16 bf16;
typedef bf16  bf16x4 __attribute__((ext_vector_type(4)));
typedef bf16  bf16x8 __attribute__((ext_vector_type(8)));
typedef float f32x4  __attribute__((ext_vector_type(4)));

template<int V> struct IC { static constexpr int value = V; };

__device__ __forceinline__ void gll16(const bf16* g, bf16* l) {
    __builtin_amdgcn_global_load_lds(
        (const __attribute__((address_space(1))) void*)g,
        (__attribute__((address_space(3))) void*)l, 16, 0, 0);
}

template<int VM> __device__ __forceinline__ void vmwait() {
    if constexpr (VM == 0)  asm volatile("s_waitcnt vmcnt(0)" ::: "memory");
    if constexpr (VM == 4)  asm volatile("s_waitcnt vmcnt(4)" ::: "memory");
    if constexpr (VM == 6)  asm volatile("s_waitcnt vmcnt(6)" ::: "memory");
    if constexpr (VM == 8)  asm volatile("s_waitcnt vmcnt(8)" ::: "memory");
    if constexpr (VM == 12) asm volatile("s_waitcnt vmcnt(12)" ::: "memory");
}

// ------------- preprocessing: weight transposes (+bf16) AND LayerNorm, one launch
__global__ __launch_bounds__(256) void pre_kernel(
    const float* __restrict__ x, const float* __restrict__ lw,
    const float* __restrict__ lb, bf16* __restrict__ h,
    const float* __restrict__ W1, const float* __restrict__ W2,
    bf16* __restrict__ Bt1, bf16* __restrict__ Bt2) {
    __shared__ float sm[32][33];
    int bid = blockIdx.x;
    int t = threadIdx.x;
    if (bid < 6400) {            // weight transpose path
        const float* W; bf16* Bt; int K, N, NP, bx, by;
        if (bid < 4352) {        // W1: 136 x 32 tile-grid
            W = W1; Bt = Bt1; K = 1024; N = 4256; NP = 4352;
            bx = bid % 136; by = bid / 136;
        } else {                 // W2: 32 x 64 tile-grid
            int b2 = bid - 4352;
            W = W2; Bt = Bt2; K = 2048; N = 1024; NP = 1024;
            bx = b2 % 32; by = b2 / 32;
        }
        int n0 = bx * 32, k0 = by * 32;
        int tx = t & 31, ty = t >> 5;   // 32 x 8 staging (coalesced fp32 reads)
        for (int i = 0; i < 4; i++) {
            int k = k0 + ty + i * 8, n = n0 + tx;
            sm[ty + i * 8][tx] = (n < N) ? W[(size_t)k * N + n] : 0.f;
        }
        __syncthreads();
        int nl = t >> 3, kg = (t & 7) * 4;
        int n = n0 + nl;
        if (n < NP) {
            bf16x4 v;
            #pragma unroll
            for (int j = 0; j < 4; j++) v[j] = (bf16)sm[kg + j][nl];
            *(bf16x4*)&Bt[(size_t)n * K + k0 + kg] = v;
        }
        return;
    }
    // LayerNorm path
    int row = bid - 6400;
    const float* xr = x + (size_t)row * DMODEL;
    bf16* hr = h + (size_t)row * DMODEL;
    float4 v = ((const float4*)xr)[t];
    float s  = v.x + v.y + v.z + v.w;
    float ss = v.x*v.x + v.y*v.y + v.z*v.z + v.w*v.w;
    for (int o = 32; o > 0; o >>= 1) { s += __shfl_down(s, o); ss += __shfl_down(ss, o); }
    int wid = t >> 6, lane = t & 63;
    if (lane == 0) { sm[0][wid] = s; sm[1][wid] = ss; }
    __syncthreads();
    if (t == 0) {
        float a = 0, b2 = 0;
        for (int i = 0; i < 4; i++) { a += sm[0][i]; b2 += sm[1][i]; }
        sm[0][0] = a; sm[1][0] = b2;
    }
    __syncthreads();
    float mean = sm[0][0] * (1.f / DMODEL);
    float var  = sm[1][0] * (1.f / DMODEL) - mean * mean;
    float rstd = rsqrtf(var + EPSF);
    float4 wv = ((const float4*)lw)[t];
    float4 bv = ((const float4*)lb)[t];
    bf16x4 o;
    o[0] = (bf16)((v.x - mean) * rstd * wv.x + bv.x);
    o[1] = (bf16)((v.y - mean) * rstd * wv.y + bv.y);
    o[2] = (bf16)((v.z - mean) * rstd * wv.z + bv.z);
    o[3] = (bf16)((v.w - mean) * rstd * wv.w + bv.w);
    *(bf16x4*)&hr[t * 4] = o;
}

// ---------------- bf16 MFMA GEMM, 3-deep ring pipeline (T4 counted vmcnt)
// Grid: (M/BM fast, N/BN slow) -> consecutive blocks share the B n-panel.
template<int BM, int BN, typename OUT_T>
__global__ __launch_bounds__(256) void gemm_bf16_pipe3(
    const bf16* __restrict__ A, const bf16* __restrict__ Bt,
    OUT_T* __restrict__ C, int M, int N, int K,
    const float* __restrict__ resid) {
    constexpr int MR = BM / 32;
    constexpr int NR = BN / 32;
    constexpr int LPT = BM / 64 + BN / 64;   // gll16 per thread per tile
    __shared__ __align__(16) bf16 sA[3][BM * 32];
    __shared__ __align__(16) bf16 sB[3][BN * 32];
    int t = threadIdx.x;
    int lane = t & 63, w = t >> 6;
    int m0 = blockIdx.x * BM, n0 = blockIdx.y * BN;
    int wm = w >> 1, wn = w & 1;
    f32x4 acc[MR][NR] = {};
    int srow = w * 16 + (lane >> 2);
    int scol = (lane & 3) * 8;
    int fr = lane & 15;
    int fc = (lane >> 4) * 8;
    auto stage = [&](int buf, int k0) {
        #pragma unroll
        for (int i = 0; i < BM / 64; i++)
            gll16(&A[(size_t)(m0 + i * 64 + srow) * K + k0 + scol],
                  &sA[buf][(i * 64 + w * 16) * 32]);
        #pragma unroll
        for (int i = 0; i < BN / 64; i++)
            gll16(&Bt[(size_t)(n0 + i * 64 + srow) * K + k0 + scol],
                  &sB[buf][(i * 64 + w * 16) * 32]);
    };
    int nt = K / 32;
    stage(0, 0); stage(1, 32); stage(2, 64);     // 3 tiles in flight
    int tt = 0;
    auto iter = [&](auto vmtag) {
        constexpr int VM = decltype(vmtag)::value;
        vmwait<VM>();                            // own tile-tt loads landed
        __builtin_amdgcn_s_barrier();            // ...for ALL waves -> buf ready
        int buf = tt % 3;
        bf16x8 af[MR], bfr[NR];
        #pragma unroll
        for (int i = 0; i < MR; i++)
            af[i] = *(const bf16x8*)&sA[buf][(wm * (BM/2) + i * 16 + fr) * 32 + fc];
        #pragma unroll
        for (int j = 0; j < NR; j++)
            bfr[j] = *(const bf16x8*)&sB[buf][(wn * (BN/2) + j * 16 + fr) * 32 + fc];
        asm volatile("s_waitcnt lgkmcnt(0)" ::: "memory");   // reads returned
        __builtin_amdgcn_sched_barrier(0);
        __builtin_amdgcn_s_barrier();            // all waves done reading buf
        if (tt + 3 < nt) stage(buf, (tt + 3) * 32);          // reuse ring slot
        #pragma unroll
        for (int i = 0; i < MR; i++)
            #pragma unroll
            for (int j = 0; j < NR; j++)
                acc[i][j] = __builtin_amdgcn_mfma_f32_16x16x32_bf16(
                    af[i], bfr[j], acc[i][j], 0, 0, 0);
        tt++;
    };
    for (; tt < nt - 2; ) iter(IC<2 * LPT>{});
    iter(IC<LPT>{});
    iter(IC<0>{});
    #pragma unroll
    for (int i = 0; i < MR; i++) {
        #pragma unroll
        for (int j = 0; j < NR; j++) {
            int col = n0 + wn * (BN/2) + j * 16 + (lane & 15);
            #pragma unroll
            for (int r = 0; r < 4; r++) {
                int row = m0 + wm * (BM/2) + i * 16 + (lane >> 4) * 4 + r;
                float v = acc[i][j][r];
                if (resid) v += resid[(size_t)row * N + col];
                C[(size_t)row * N + col] = (OUT_T)v;
            }
        }
    }
}

// --------- causal depthwise conv + SiLU + dt softplus, VECTORIZED (8 ch/thread)
__global__ __launch_bounds__(256) void convdt_kernel(
    const bf16* __restrict__ zx, const float* __restrict__ cw,
    const float* __restrict__ cb, const float* __restrict__ dt_bias,
    bf16* __restrict__ xs, bf16* __restrict__ Bm, bf16* __restrict__ Cm,
    float* __restrict__ dtb) {
    int idx = blockIdx.x * 256 + threadIdx.x;        // 4096 * NG
    int g = idx % NG;
    int bl = idx / NG;
    int b = bl / SEQ, tt = bl % SEQ;
    const bf16* zrow = zx + (size_t)(b * SEQ) * NPAD + DINNER;
    if (g >= 272) {                                  // dt path: 8 heads
        int hh0 = (g - 272) * 8;
        bf16x8 v = *(const bf16x8*)&zx[(size_t)bl * NPAD + DINNER + CONVDIM + hh0];
        float4 o0, o1;
        #pragma unroll
        for (int i = 0; i < 8; i++) {
            float u = (float)v[i] + dt_bias[hh0 + i];
            ((i < 4) ? ((float*)&o0) : ((float*)&o1))[i & 3] =
                (u > 20.f) ? u : log1pf(expf(u));
        }
        *(float4*)&dtb[bl * NHEADS + hh0]     = o0;
        *(float4*)&dtb[bl * NHEADS + hh0 + 4] = o1;
        return;
    }
    int ch0 = g * 8;
    float acc[8];
    {
        float4 c0 = *(const float4*)&cb[ch0];
        float4 c1 = *(const float4*)&cb[ch0 + 4];
        acc[0]=c0.x; acc[1]=c0.y; acc[2]=c0.z; acc[3]=c0.w;
        acc[4]=c1.x; acc[5]=c1.y; acc[6]=c1.z; acc[7]=c1.w;
    }
    float4 cwv[8];                                   // cw[ch][4], 8 channels
    #pragma unroll
    for (int i = 0; i < 8; i++) cwv[i] = *(const float4*)&cw[(ch0 + i) * 4];
    #pragma unroll
    for (int k = 0; k < 4; k++) {
        int tp = tt - 3 + k;
        if (tp >= 0) {
            bf16x8 v = *(const bf16x8*)&zrow[(size_t)tp * NPAD + ch0];
            #pragma unroll
            for (int i = 0; i < 8; i++)
                acc[i] += (float)v[i] * ((const float*)&cwv[i])[k];
        }
    }
    bf16x8 o;
    #pragma unroll
    for (int i = 0; i < 8; i++) {
        float s = acc[i] / (1.f + expf(-acc[i]));
        o[i] = (bf16)s;
    }
    if (ch0 < DINNER)              *(bf16x8*)&xs[(size_t)bl * DINNER + ch0] = o;
    else if (ch0 < DINNER+DSTATE)  *(bf16x8*)&Bm[bl * DSTATE + (ch0 - DINNER)] = o;
    else                           *(bf16x8*)&Cm[bl * DSTATE + (ch0 - DINNER - DSTATE)] = o;
}

// ----------------------------------------- SSD: per-chunk local states (MFMA)
__global__ __launch_bounds__(256) void ssd_states_kernel(
    const bf16* __restrict__ xs, const bf16* __restrict__ Bm,
    const float* __restrict__ dtb, const float* __restrict__ A_log,
    bf16* __restrict__ states, float* __restrict__ Acs_g) {
    int blk = blockIdx.x;
    int hh = blk % NHEADS;
    int bc = blk / NHEADS;
    int c = bc % NCHUNK, b = bc / NCHUNK;
    __shared__ __align__(16) bf16 sXT[64 * SP];   // [p][l]
    __shared__ __align__(16) bf16 sBT[64 * SP];   // [n][l]
    __shared__ float dts[64], acs[64];
    int t = threadIdx.x;
    float Ah = -expf(A_log[hh]);
    if (t < 64) {                                // wave 0: load + parallel scan
        float dv = dtb[(b * SEQ + c * 64 + t) * NHEADS + hh];
        float v = dv * Ah;
        #pragma unroll
        for (int o = 1; o < 64; o <<= 1) {
            float p = __shfl_up(v, o);
            if (t >= o) v += p;
        }
        dts[t] = dv; acs[t] = v;
        Acs_g[((b * NHEADS + hh) * NCHUNK + c) * 64 + t] = v;
    }
    __syncthreads();
    float alast = acs[63];
    {   // stage transposed, weighted
        int l = t >> 2, c0 = (t & 3) * 16;
        int row = b * SEQ + c * 64 + l;
        float dl = dts[l];
        float wl = expf(alast - acs[l]);
        bf16x8 xv0 = *(const bf16x8*)&xs[(size_t)row * DINNER + hh * 64 + c0];
        bf16x8 xv1 = *(const bf16x8*)&xs[(size_t)row * DINNER + hh * 64 + c0 + 8];
        bf16x8 bv0 = *(const bf16x8*)&Bm[(size_t)row * DSTATE + c0];
        bf16x8 bv1 = *(const bf16x8*)&Bm[(size_t)row * DSTATE + c0 + 8];
        #pragma unroll
        for (int i = 0; i < 8; i++) {
            sXT[(c0 + i) * SP + l]     = (bf16)((float)xv0[i] * dl);
            sXT[(c0 + 8 + i) * SP + l] = (bf16)((float)xv1[i] * dl);
            sBT[(c0 + i) * SP + l]     = (bf16)((float)bv0[i] * wl);
            sBT[(c0 + 8 + i) * SP + l] = (bf16)((float)bv1[i] * wl);
        }
    }
    __syncthreads();
    int lane = t & 63, w = t >> 6;
    int wm = w >> 1, wn = w & 1;
    int fr = lane & 15, fc = (lane >> 4) * 8;
    f32x4 acc[2][2] = {};
    #pragma unroll
    for (int kk = 0; kk < 2; kk++) {
        bf16x8 a[2], bb[2];
        #pragma unroll
        for (int i = 0; i < 2; i++)
            a[i] = *(const bf16x8*)&sXT[(wm * 32 + i * 16 + fr) * SP + kk * 32 + fc];
        #pragma unroll
        for (int j = 0; j < 2; j++)
            bb[j] = *(const bf16x8*)&sBT[(wn * 32 + j * 16 + fr) * SP + kk * 32 + fc];
        #pragma unroll
        for (int i = 0; i < 2; i++)
            #pragma unroll
            for (int j = 0; j < 2; j++)
                acc[i][j] = __builtin_amdgcn_mfma_f32_16x16x32_bf16(
                    a[i], bb[j], acc[i][j], 0, 0, 0);
    }
    bf16* outp = states + (size_t)blk * 4096;
    #pragma unroll
    for (int i = 0; i < 2; i++)
        #pragma unroll
        for (int j = 0; j < 2; j++)
            #pragma unroll
            for (int r = 0; r < 4; r++)
                outp[(wm*32 + i*16 + (lane>>4)*4 + r) * 64 + wn*32 + j*16 + (lane&15)]
                    = (bf16)acc[i][j][r];
}

// ------------------------------------------- SSD: inter-chunk sequential scan
__global__ __launch_bounds__(256) void ssd_scan_kernel(
    bf16* __restrict__ states, const float* __restrict__ Acs_g) {
    int bid = blockIdx.x;
    int slice = bid & 3, bh = bid >> 2;
    int hh = bh % NHEADS, b = bh / NHEADS;
    int e0 = slice * 1024 + threadIdx.x * 4;
    bf16x4 loc[NCHUNK];
    float dec[NCHUNK];
    #pragma unroll
    for (int c = 0; c < NCHUNK; c++) {
        loc[c] = *(const bf16x4*)&states[(size_t)((b*NCHUNK+c)*NHEADS+hh)*4096 + e0];
        dec[c] = expf(Acs_g[((b*NHEADS+hh)*NCHUNK + c)*64 + 63]);
    }
    float S0 = 0.f, S1 = 0.f, S2 = 0.f, S3 = 0.f;
    #pragma unroll
    for (int c = 0; c < NCHUNK; c++) {
        bf16x4 l = loc[c];
        bf16x4 o; o[0] = (bf16)S0; o[1] = (bf16)S1; o[2] = (bf16)S2; o[3] = (bf16)S3;
        *(bf16x4*)&states[(size_t)((b*NCHUNK+c)*NHEADS+hh)*4096 + e0] = o;
        S0 = dec[c]*S0 + (float)l[0];
        S1 = dec[c]*S1 + (float)l[1];
        S2 = dec[c]*S2 + (float)l[2];
        S3 = dec[c]*S3 + (float)l[3];
    }
}

// --------------------------------- SSD: Y = Y_diag + Y_off + D*X (MFMA) -> bf16
__global__ __launch_bounds__(256) void ssd_out_kernel(
    const bf16* __restrict__ xs, const bf16* __restrict__ Bm,
    const bf16* __restrict__ Cm, const float* __restrict__ dtb,
    const bf16* __restrict__ states, const float* __restrict__ Acs_g,
    const float* __restrict__ Dv, bf16* __restrict__ Y) {
    int blk = blockIdx.x;
    int hh = blk % NHEADS;
    int bc = blk / NHEADS;
    int c = bc % NCHUNK, b = bc / NCHUNK;
    __shared__ __align__(16) bf16 sC [64 * SP];   // [l][n]
    __shared__ __align__(16) bf16 sBG[64 * SP];   // B[s][n] -> G'[l][s]
    __shared__ __align__(16) bf16 sXS[64 * SP];   // X^T[p][l] -> S[p][n]
    __shared__ float acs[64], dts[64];
    int t = threadIdx.x;
    bf16x8 sreg0, sreg1;                          // T14: S prefetch to regs
    {
        const bf16* sp = states + (size_t)blk * 4096 + t * 16;
        sreg0 = *(const bf16x8*)&sp[0];
        sreg1 = *(const bf16x8*)&sp[8];
    }
    if (t < 64) {
        acs[t] = Acs_g[((b * NHEADS + hh) * NCHUNK + c) * 64 + t];
        dts[t] = dtb[(b * SEQ + c * 64 + t) * NHEADS + hh];
    }
    {   // stage C, B natural; X transposed (raw)
        int l = t >> 2, c0 = (t & 3) * 16;
        int row = b * SEQ + c * 64 + l;
        *(bf16x8*)&sC[l * SP + c0]      = *(const bf16x8*)&Cm[(size_t)row * DSTATE + c0];
        *(bf16x8*)&sC[l * SP + c0 + 8]  = *(const bf16x8*)&Cm[(size_t)row * DSTATE + c0 + 8];
        *(bf16x8*)&sBG[l * SP + c0]     = *(const bf16x8*)&Bm[(size_t)row * DSTATE + c0];
        *(bf16x8*)&sBG[l * SP + c0 + 8] = *(const bf16x8*)&Bm[(size_t)row * DSTATE + c0 + 8];
        bf16x8 xv0 = *(const bf16x8*)&xs[(size_t)row * DINNER + hh * 64 + c0];
        bf16x8 xv1 = *(const bf16x8*)&xs[(size_t)row * DINNER + hh * 64 + c0 + 8];
        #pragma unroll
        for (int i = 0; i < 8; i++) {
            sXS[(c0 + i) * SP + l]     = xv0[i];
            sXS[(c0 + 8 + i) * SP + l] = xv1[i];
        }
    }
    __syncthreads();
    int lane = t & 63, w = t >> 6;
    int wm = w >> 1, wn = w & 1;
    int fr = lane & 15, fc = (lane >> 4) * 8;
    // ---- m1: G0 = C . B^T
    f32x4 g[2][2] = {};
    #pragma unroll
    for (int kk = 0; kk < 2; kk++) {
        bf16x8 a[2], bb[2];
        #pragma unroll
        for (int i = 0; i < 2; i++)
            a[i] = *(const bf16x8*)&sC[(wm * 32 + i * 16 + fr) * SP + kk * 32 + fc];
        #pragma unroll
        for (int j = 0; j < 2; j++)
            bb[j] = *(const bf16x8*)&sBG[(wn * 32 + j * 16 + fr) * SP + kk * 32 + fc];
        #pragma unroll
        for (int i = 0; i < 2; i++)
            #pragma unroll
            for (int j = 0; j < 2; j++)
                g[i][j] = __builtin_amdgcn_mfma_f32_16x16x32_bf16(a[i], bb[j], g[i][j], 0, 0, 0);
    }
    __syncthreads();           // all m1 reads of B done
    // ---- G' = tril(G0 * exp(acs_l - acs_s)) * dt_s
    #pragma unroll
    for (int i = 0; i < 2; i++) {
        #pragma unroll
        for (int j = 0; j < 2; j++) {
            int s = wn * 32 + j * 16 + (lane & 15);
            #pragma unroll
            for (int r = 0; r < 4; r++) {
                int l = wm * 32 + i * 16 + (lane >> 4) * 4 + r;
                float val = (s <= l) ? g[i][j][r] * expf(acs[l] - acs[s]) * dts[s] : 0.f;
                sBG[l * SP + s] = (bf16)val;
            }
        }
    }
    __syncthreads();           // G' visible
    // ---- m2: Y_diag = G' . X
    f32x4 yd[2][2] = {};
    #pragma unroll
    for (int kk = 0; kk < 2; kk++) {
        bf16x8 a[2], bb[2];
        #pragma unroll
        for (int i = 0; i < 2; i++)
            a[i] = *(const bf16x8*)&sBG[(wm * 32 + i * 16 + fr) * SP + kk * 32 + fc];
        #pragma unroll
        for (int j = 0; j < 2; j++)
            bb[j] = *(const bf16x8*)&sXS[(wn * 32 + j * 16 + fr) * SP + kk * 32 + fc];
        #pragma unroll
        for (int i = 0; i < 2; i++)
            #pragma unroll
            for (int j = 0; j < 2; j++)
                yd[i][j] = __builtin_amdgcn_mfma_f32_16x16x32_bf16(a[i], bb[j], yd[i][j], 0, 0, 0);
    }
    // raw X at output positions (D-skip), before sXS is overwritten
    float xk[2][2][4];
    #pragma unroll
    for (int i = 0; i < 2; i++)
        #pragma unroll
        for (int j = 0; j < 2; j++) {
            int p = wn * 32 + j * 16 + (lane & 15);
            #pragma unroll
            for (int r = 0; r < 4; r++) {
                int l = wm * 32 + i * 16 + (lane >> 4) * 4 + r;
                xk[i][j][r] = (float)sXS[p * SP + l];
            }
        }
    __syncthreads();           // all sXS (X^T) reads done
    {   // overwrite sXS with S_in [p][n]
        int p = t >> 2, n0 = (t & 3) * 16;
        *(bf16x8*)&sXS[p * SP + n0]     = sreg0;
        *(bf16x8*)&sXS[p * SP + n0 + 8] = sreg1;
    }
    __syncthreads();
    // ---- m3: Y_off = C . S^T
    f32x4 yo[2][2] = {};
    #pragma unroll
    for (int kk = 0; kk < 2; kk++) {
        bf16x8 a[2], bb[2];
        #pragma unroll
        for (int i = 0; i < 2; i++)
            a[i] = *(const bf16x8*)&sC[(wm * 32 + i * 16 + fr) * SP + kk * 32 + fc];
        #pragma unroll
        for (int j = 0; j < 2; j++)
            bb[j] = *(const bf16x8*)&sXS[(wn * 32 + j * 16 + fr) * SP + kk * 32 + fc];
        #pragma unroll
        for (int i = 0; i < 2; i++)
            #pragma unroll
            for (int j = 0; j < 2; j++)
                yo[i][j] = __builtin_amdgcn_mfma_f32_16x16x32_bf16(a[i], bb[j], yo[i][j], 0, 0, 0);
    }
    float Dh = Dv[hh];
    #pragma unroll
    for (int i = 0; i < 2; i++) {
        #pragma unroll
        for (int j = 0; j < 2; j++) {
            int p = wn * 32 + j * 16 + (lane & 15);
            #pragma unroll
            for (int r = 0; r < 4; r++) {
                int l = wm * 32 + i * 16 + (lane >> 4) * 4 + r;
                int row = b * SEQ + c * 64 + l;
                Y[(size_t)row * DINNER + hh * 64 + p] =
                    (bf16)(yd[i][j][r] + expf(acs[l]) * yo[i][j][r] + Dh * xk[i][j][r]);
            }
        }
    }
}

// --------------------------------------------------- gated RMSNorm -> bf16 (vec)
__global__ __launch_bounds__(256) void rms_kernel(
    const bf16* __restrict__ Y, const bf16* __restrict__ zx,
    const float* __restrict__ nw, bf16* __restrict__ yn) {
    int row = blockIdx.x;
    const bf16* yr = Y + (size_t)row * DINNER;
    const bf16* zr = zx + (size_t)row * NPAD;       // z = cols [0, 2048)
    bf16* outr = yn + (size_t)row * DINNER;
    int t = threadIdx.x;
    bf16x8 yv = *(const bf16x8*)&yr[t * 8];
    bf16x8 zv = *(const bf16x8*)&zr[t * 8];
    float vals[8];
    float ss = 0.f;
    #pragma unroll
    for (int i = 0; i < 8; i++) {
        float z = (float)zv[i];
        float v = (float)yv[i] * (z / (1.f + expf(-z)));
        vals[i] = v;
        ss += v * v;
    }
    for (int o = 32; o > 0; o >>= 1) ss += __shfl_down(ss, o);
    __shared__ float red[4];
    int wid = t >> 6, lane = t & 63;
    if (lane == 0) red[wid] = ss;
    __syncthreads();
    if (t == 0) { float a = 0; for (int i = 0; i < 4; i++) a += red[i]; red[0] = a; }
    __syncthreads();
    float r = rsqrtf(red[0] * (1.f / DINNER) + EPSF);
    float4 w0 = *(const float4*)&nw[t * 8];
    float4 w1 = *(const float4*)&nw[t * 8 + 4];
    bf16x8 o;
    const float* wp0 = (const float*)&w0;
    const float* wp1 = (const float*)&w1;
    #pragma unroll
    for (int i = 0; i < 8; i++)
        o[i] = (bf16)(vals[i] * r * ((i < 4) ? wp0[i] : wp1[i - 4]));
    *(bf16x8*)&outr[t * 8] = o;
}

// ---------------------------------------------------------------------------
extern "C" void kernel_launch(void* const* d_in, const int* in_sizes, int n_in,
                              void* d_out, int out_size, void* d_ws, size_t ws_size,
                              hipStream_t stream) {
    const float* x          = (const float*)d_in[0];
    const float* ln_w       = (const float*)d_in[1];
    const float* ln_b       = (const float*)d_in[2];
    const float* in_proj_w  = (const float*)d_in[3];
    const float* conv_w     = (const float*)d_in[4];
    const float* conv_b     = (const float*)d_in[5];
    const float* dt_bias    = (const float*)d_in[6];
    const float* A_log      = (const float*)d_in[7];
    const float* Dv         = (const float*)d_in[8];
    const float* norm_w     = (const float*)d_in[9];
    const float* out_proj_w = (const float*)d_in[10];
    float* out = (float*)d_out;

    char* ws = (char*)d_ws;
    size_t off = 0;
    auto alloc = [&](size_t bytes) { char* p = ws + off; off += (bytes + 255) & ~(size_t)255; return p; };
    bf16*  h_bf  = (bf16*) alloc((size_t)4096 * DMODEL * 2);     //  8.4 MB
    bf16*  zx    = (bf16*) alloc((size_t)4096 * NPAD * 2);       // 35.6 MB
    bf16*  xs    = (bf16*) alloc((size_t)4096 * DINNER * 2);     // 16.8 MB
    bf16*  states= (bf16*) alloc((size_t)2048 * 4096 * 2);       // 16.8 MB
    bf16*  Yb    = (bf16*) alloc((size_t)4096 * DINNER * 2);     // 16.8 MB
    bf16*  Bt1   = (bf16*) alloc((size_t)NPAD * DMODEL * 2);     //  8.9 MB
    bf16*  Bt2   = (bf16*) alloc((size_t)DMODEL * DINNER * 2);   //  4.2 MB
    float* dtb   = (float*)alloc((size_t)4096 * NHEADS * 4);     //  0.5 MB
    float* Acs   = (float*)alloc((size_t)2 * NHEADS * NCHUNK * 64 * 4);
    bf16* Bm = h_bf;                          // h_bf dead after GEMM1
    bf16* Cm = h_bf + (size_t)4096 * DSTATE;
    bf16* yn = xs;                            // xs dead after ssd_out

    // weight transposes + LayerNorm, one launch
    pre_kernel<<<6400 + 4096, 256, 0, stream>>>(
        x, ln_w, ln_b, h_bf, in_proj_w, out_proj_w, Bt1, Bt2);

    {   // zx = h @ in_proj_w   (bf16 out); 256x128 tiles, m-fast grid
        dim3 g((BATCH * SEQ) / 256, NPAD / 128);
        gemm_bf16_pipe3<256, 128, bf16><<<g, 256, 0, stream>>>(
            h_bf, Bt1, zx, BATCH * SEQ, NPAD, DMODEL, nullptr);
    }

    convdt_kernel<<<(BATCH * SEQ * NG) / 256, 256, 0, stream>>>(
        zx, conv_w, conv_b, dt_bias, xs, Bm, Cm, dtb);

    ssd_states_kernel<<<BATCH * NCHUNK * NHEADS, 256, 0, stream>>>(
        xs, Bm, dtb, A_log, states, Acs);

    ssd_scan_kernel<<<BATCH * NHEADS * 4, 256, 0, stream>>>(states, Acs);

    ssd_out_kernel<<<BATCH * NCHUNK * NHEADS, 256, 0, stream>>>(
        xs, Bm, Cm, dtb, states, Acs, Dv, Yb);

    rms_kernel<<<BATCH * SEQ, 256, 0, stream>>>(Yb, zx, norm_w, yn);

    {   // out = yn @ out_proj_w + x; 128x128 tiles, m-fast grid (256 blocks)
        dim3 g((BATCH * SEQ) / 128, DMODEL / 128);
        gemm_bf16_pipe3<128, 128, float><<<g, 256, 0, stream>>>(
            yn, Bt2, out, BATCH * SEQ, DMODEL, DINNER, x);
    }
}

// Round 11
// 195.866 us; speedup vs baseline: 1.2438x; 1.2438x over previous
//
#include <hip/hip_runtime.h>
#include <hip/hip_bf16.h>

#define BATCH   2
#define SEQ     2048
#define DMODEL  1024
#define DINNER  2048
#define DSTATE  64
#define NHEADS  32
#define HEADDIM 64
#define CONVDIM 2176
#define DINPROJ 4256
#define NPAD    4352        // DINPROJ padded to 34*128 for the MFMA GEMM
#define NCHUNK  32          // SEQ / 64
#define EPSF    1e-5f
#define SP      88          // LDS row stride (bf16) for SSD kernels
#define NG      276         // (CONVDIM + NHEADS) / 8 channel-groups per row

typedef __bf16 bf16;
typedef bf16  bf16x4 __attribute__((ext_vector_type(4)));
typedef bf16  bf16x8 __attribute__((ext_vector_type(8)));
typedef float f32x4  __attribute__((ext_vector_type(4)));

template<int V> struct IC { static constexpr int value = V; };

__device__ __forceinline__ void gll16(const bf16* g, bf16* l) {
    __builtin_amdgcn_global_load_lds(
        (const __attribute__((address_space(1))) void*)g,
        (__attribute__((address_space(3))) void*)l, 16, 0, 0);
}

template<int VM> __device__ __forceinline__ void vmwait() {
    if constexpr (VM == 0)  asm volatile("s_waitcnt vmcnt(0)" ::: "memory");
    if constexpr (VM == 4)  asm volatile("s_waitcnt vmcnt(4)" ::: "memory");
    if constexpr (VM == 6)  asm volatile("s_waitcnt vmcnt(6)" ::: "memory");
    if constexpr (VM == 8)  asm volatile("s_waitcnt vmcnt(8)" ::: "memory");
    if constexpr (VM == 12) asm volatile("s_waitcnt vmcnt(12)" ::: "memory");
}

// ------------- preprocessing: weight transposes (+bf16) AND LayerNorm, one launch
__global__ __launch_bounds__(256) void pre_kernel(
    const float* __restrict__ x, const float* __restrict__ lw,
    const float* __restrict__ lb, bf16* __restrict__ h,
    const float* __restrict__ W1, const float* __restrict__ W2,
    bf16* __restrict__ Bt1, bf16* __restrict__ Bt2) {
    __shared__ float sm[32][33];
    int bid = blockIdx.x;
    int t = threadIdx.x;
    if (bid < 6400) {            // weight transpose path
        const float* W; bf16* Bt; int K, N, NP, bx, by;
        if (bid < 4352) {        // W1: 136 x 32 tile-grid
            W = W1; Bt = Bt1; K = 1024; N = 4256; NP = 4352;
            bx = bid % 136; by = bid / 136;
        } else {                 // W2: 32 x 64 tile-grid
            int b2 = bid - 4352;
            W = W2; Bt = Bt2; K = 2048; N = 1024; NP = 1024;
            bx = b2 % 32; by = b2 / 32;
        }
        int n0 = bx * 32, k0 = by * 32;
        int tx = t & 31, ty = t >> 5;   // 32 x 8 staging (coalesced fp32 reads)
        for (int i = 0; i < 4; i++) {
            int k = k0 + ty + i * 8, n = n0 + tx;
            sm[ty + i * 8][tx] = (n < N) ? W[(size_t)k * N + n] : 0.f;
        }
        __syncthreads();
        int nl = t >> 3, kg = (t & 7) * 4;
        int n = n0 + nl;
        if (n < NP) {
            bf16x4 v;
            #pragma unroll
            for (int j = 0; j < 4; j++) v[j] = (bf16)sm[kg + j][nl];
            *(bf16x4*)&Bt[(size_t)n * K + k0 + kg] = v;
        }
        return;
    }
    // LayerNorm path
    int row = bid - 6400;
    const float* xr = x + (size_t)row * DMODEL;
    bf16* hr = h + (size_t)row * DMODEL;
    float4 v = ((const float4*)xr)[t];
    float s  = v.x + v.y + v.z + v.w;
    float ss = v.x*v.x + v.y*v.y + v.z*v.z + v.w*v.w;
    for (int o = 32; o > 0; o >>= 1) { s += __shfl_down(s, o); ss += __shfl_down(ss, o); }
    int wid = t >> 6, lane = t & 63;
    if (lane == 0) { sm[0][wid] = s; sm[1][wid] = ss; }
    __syncthreads();
    if (t == 0) {
        float a = 0, b2 = 0;
        for (int i = 0; i < 4; i++) { a += sm[0][i]; b2 += sm[1][i]; }
        sm[0][0] = a; sm[1][0] = b2;
    }
    __syncthreads();
    float mean = sm[0][0] * (1.f / DMODEL);
    float var  = sm[1][0] * (1.f / DMODEL) - mean * mean;
    float rstd = rsqrtf(var + EPSF);
    float4 wv = ((const float4*)lw)[t];
    float4 bv = ((const float4*)lb)[t];
    bf16x4 o;
    o[0] = (bf16)((v.x - mean) * rstd * wv.x + bv.x);
    o[1] = (bf16)((v.y - mean) * rstd * wv.y + bv.y);
    o[2] = (bf16)((v.z - mean) * rstd * wv.z + bv.z);
    o[3] = (bf16)((v.w - mean) * rstd * wv.w + bv.w);
    *(bf16x4*)&hr[t * 4] = o;
}

// ---------------- bf16 MFMA GEMM, 3-deep ring pipeline (T4 counted vmcnt)
// Grid: (M/BM fast, N/BN slow) -> consecutive blocks share the B n-panel.
template<int BM, int BN, typename OUT_T>
__global__ __launch_bounds__(256) void gemm_bf16_pipe3(
    const bf16* __restrict__ A, const bf16* __restrict__ Bt,
    OUT_T* __restrict__ C, int M, int N, int K,
    const float* __restrict__ resid) {
    constexpr int MR = BM / 32;
    constexpr int NR = BN / 32;
    constexpr int LPT = BM / 64 + BN / 64;   // gll16 per thread per tile
    __shared__ __align__(16) bf16 sA[3][BM * 32];
    __shared__ __align__(16) bf16 sB[3][BN * 32];
    int t = threadIdx.x;
    int lane = t & 63, w = t >> 6;
    int m0 = blockIdx.x * BM, n0 = blockIdx.y * BN;
    int wm = w >> 1, wn = w & 1;
    f32x4 acc[MR][NR] = {};
    int srow = w * 16 + (lane >> 2);
    int scol = (lane & 3) * 8;
    int fr = lane & 15;
    int fc = (lane >> 4) * 8;
    auto stage = [&](int buf, int k0) {
        #pragma unroll
        for (int i = 0; i < BM / 64; i++)
            gll16(&A[(size_t)(m0 + i * 64 + srow) * K + k0 + scol],
                  &sA[buf][(i * 64 + w * 16) * 32]);
        #pragma unroll
        for (int i = 0; i < BN / 64; i++)
            gll16(&Bt[(size_t)(n0 + i * 64 + srow) * K + k0 + scol],
                  &sB[buf][(i * 64 + w * 16) * 32]);
    };
    int nt = K / 32;
    stage(0, 0); stage(1, 32); stage(2, 64);     // 3 tiles in flight
    int tt = 0;
    auto iter = [&](auto vmtag) {
        constexpr int VM = decltype(vmtag)::value;
        vmwait<VM>();                            // own tile-tt loads landed
        __builtin_amdgcn_s_barrier();            // ...for ALL waves -> buf ready
        int buf = tt % 3;
        bf16x8 af[MR], bfr[NR];
        #pragma unroll
        for (int i = 0; i < MR; i++)
            af[i] = *(const bf16x8*)&sA[buf][(wm * (BM/2) + i * 16 + fr) * 32 + fc];
        #pragma unroll
        for (int j = 0; j < NR; j++)
            bfr[j] = *(const bf16x8*)&sB[buf][(wn * (BN/2) + j * 16 + fr) * 32 + fc];
        asm volatile("s_waitcnt lgkmcnt(0)" ::: "memory");   // reads returned
        __builtin_amdgcn_sched_barrier(0);
        __builtin_amdgcn_s_barrier();            // all waves done reading buf
        if (tt + 3 < nt) stage(buf, (tt + 3) * 32);          // reuse ring slot
        #pragma unroll
        for (int i = 0; i < MR; i++)
            #pragma unroll
            for (int j = 0; j < NR; j++)
                acc[i][j] = __builtin_amdgcn_mfma_f32_16x16x32_bf16(
                    af[i], bfr[j], acc[i][j], 0, 0, 0);
        tt++;
    };
    for (; tt < nt - 2; ) iter(IC<2 * LPT>{});
    iter(IC<LPT>{});
    iter(IC<0>{});
    #pragma unroll
    for (int i = 0; i < MR; i++) {
        #pragma unroll
        for (int j = 0; j < NR; j++) {
            int col = n0 + wn * (BN/2) + j * 16 + (lane & 15);
            #pragma unroll
            for (int r = 0; r < 4; r++) {
                int row = m0 + wm * (BM/2) + i * 16 + (lane >> 4) * 4 + r;
                float v = acc[i][j][r];
                if (resid) v += resid[(size_t)row * N + col];
                C[(size_t)row * N + col] = (OUT_T)v;
            }
        }
    }
}

// --------- causal depthwise conv + SiLU + dt softplus, VECTORIZED (8 ch/thread)
__global__ __launch_bounds__(256) void convdt_kernel(
    const bf16* __restrict__ zx, const float* __restrict__ cw,
    const float* __restrict__ cb, const float* __restrict__ dt_bias,
    bf16* __restrict__ xs, bf16* __restrict__ Bm, bf16* __restrict__ Cm,
    float* __restrict__ dtb) {
    int idx = blockIdx.x * 256 + threadIdx.x;        // 4096 * NG
    int g = idx % NG;
    int bl = idx / NG;
    int b = bl / SEQ, tt = bl % SEQ;
    const bf16* zrow = zx + (size_t)(b * SEQ) * NPAD + DINNER;
    if (g >= 272) {                                  // dt path: 8 heads
        int hh0 = (g - 272) * 8;
        bf16x8 v = *(const bf16x8*)&zx[(size_t)bl * NPAD + DINNER + CONVDIM + hh0];
        float4 o0, o1;
        #pragma unroll
        for (int i = 0; i < 8; i++) {
            float u = (float)v[i] + dt_bias[hh0 + i];
            ((i < 4) ? ((float*)&o0) : ((float*)&o1))[i & 3] =
                (u > 20.f) ? u : log1pf(expf(u));
        }
        *(float4*)&dtb[bl * NHEADS + hh0]     = o0;
        *(float4*)&dtb[bl * NHEADS + hh0 + 4] = o1;
        return;
    }
    int ch0 = g * 8;
    float acc[8];
    {
        float4 c0 = *(const float4*)&cb[ch0];
        float4 c1 = *(const float4*)&cb[ch0 + 4];
        acc[0]=c0.x; acc[1]=c0.y; acc[2]=c0.z; acc[3]=c0.w;
        acc[4]=c1.x; acc[5]=c1.y; acc[6]=c1.z; acc[7]=c1.w;
    }
    float4 cwv[8];                                   // cw[ch][4], 8 channels
    #pragma unroll
    for (int i = 0; i < 8; i++) cwv[i] = *(const float4*)&cw[(ch0 + i) * 4];
    #pragma unroll
    for (int k = 0; k < 4; k++) {
        int tp = tt - 3 + k;
        if (tp >= 0) {
            bf16x8 v = *(const bf16x8*)&zrow[(size_t)tp * NPAD + ch0];
            #pragma unroll
            for (int i = 0; i < 8; i++)
                acc[i] += (float)v[i] * ((const float*)&cwv[i])[k];
        }
    }
    bf16x8 o;
    #pragma unroll
    for (int i = 0; i < 8; i++) {
        float s = acc[i] / (1.f + expf(-acc[i]));
        o[i] = (bf16)s;
    }
    if (ch0 < DINNER)              *(bf16x8*)&xs[(size_t)bl * DINNER + ch0] = o;
    else if (ch0 < DINNER+DSTATE)  *(bf16x8*)&Bm[bl * DSTATE + (ch0 - DINNER)] = o;
    else                           *(bf16x8*)&Cm[bl * DSTATE + (ch0 - DINNER - DSTATE)] = o;
}

// ----------------------------------------- SSD: per-chunk local states (MFMA)
__global__ __launch_bounds__(256) void ssd_states_kernel(
    const bf16* __restrict__ xs, const bf16* __restrict__ Bm,
    const float* __restrict__ dtb, const float* __restrict__ A_log,
    bf16* __restrict__ states, float* __restrict__ Acs_g) {
    int blk = blockIdx.x;
    int hh = blk % NHEADS;
    int bc = blk / NHEADS;
    int c = bc % NCHUNK, b = bc / NCHUNK;
    __shared__ __align__(16) bf16 sXT[64 * SP];   // [p][l]
    __shared__ __align__(16) bf16 sBT[64 * SP];   // [n][l]
    __shared__ float dts[64], acs[64];
    int t = threadIdx.x;
    float Ah = -expf(A_log[hh]);
    if (t < 64) {                                // wave 0: load + parallel scan
        float dv = dtb[(b * SEQ + c * 64 + t) * NHEADS + hh];
        float v = dv * Ah;
        #pragma unroll
        for (int o = 1; o < 64; o <<= 1) {
            float p = __shfl_up(v, o);
            if (t >= o) v += p;
        }
        dts[t] = dv; acs[t] = v;
        Acs_g[((b * NHEADS + hh) * NCHUNK + c) * 64 + t] = v;
    }
    __syncthreads();
    float alast = acs[63];
    {   // stage transposed, weighted
        int l = t >> 2, c0 = (t & 3) * 16;
        int row = b * SEQ + c * 64 + l;
        float dl = dts[l];
        float wl = expf(alast - acs[l]);
        bf16x8 xv0 = *(const bf16x8*)&xs[(size_t)row * DINNER + hh * 64 + c0];
        bf16x8 xv1 = *(const bf16x8*)&xs[(size_t)row * DINNER + hh * 64 + c0 + 8];
        bf16x8 bv0 = *(const bf16x8*)&Bm[(size_t)row * DSTATE + c0];
        bf16x8 bv1 = *(const bf16x8*)&Bm[(size_t)row * DSTATE + c0 + 8];
        #pragma unroll
        for (int i = 0; i < 8; i++) {
            sXT[(c0 + i) * SP + l]     = (bf16)((float)xv0[i] * dl);
            sXT[(c0 + 8 + i) * SP + l] = (bf16)((float)xv1[i] * dl);
            sBT[(c0 + i) * SP + l]     = (bf16)((float)bv0[i] * wl);
            sBT[(c0 + 8 + i) * SP + l] = (bf16)((float)bv1[i] * wl);
        }
    }
    __syncthreads();
    int lane = t & 63, w = t >> 6;
    int wm = w >> 1, wn = w & 1;
    int fr = lane & 15, fc = (lane >> 4) * 8;
    f32x4 acc[2][2] = {};
    #pragma unroll
    for (int kk = 0; kk < 2; kk++) {
        bf16x8 a[2], bb[2];
        #pragma unroll
        for (int i = 0; i < 2; i++)
            a[i] = *(const bf16x8*)&sXT[(wm * 32 + i * 16 + fr) * SP + kk * 32 + fc];
        #pragma unroll
        for (int j = 0; j < 2; j++)
            bb[j] = *(const bf16x8*)&sBT[(wn * 32 + j * 16 + fr) * SP + kk * 32 + fc];
        #pragma unroll
        for (int i = 0; i < 2; i++)
            #pragma unroll
            for (int j = 0; j < 2; j++)
                acc[i][j] = __builtin_amdgcn_mfma_f32_16x16x32_bf16(
                    a[i], bb[j], acc[i][j], 0, 0, 0);
    }
    bf16* outp = states + (size_t)blk * 4096;
    #pragma unroll
    for (int i = 0; i < 2; i++)
        #pragma unroll
        for (int j = 0; j < 2; j++)
            #pragma unroll
            for (int r = 0; r < 4; r++)
                outp[(wm*32 + i*16 + (lane>>4)*4 + r) * 64 + wn*32 + j*16 + (lane&15)]
                    = (bf16)acc[i][j][r];
}

// ------------------------------------------- SSD: inter-chunk sequential scan
__global__ __launch_bounds__(256) void ssd_scan_kernel(
    bf16* __restrict__ states, const float* __restrict__ Acs_g) {
    int bid = blockIdx.x;
    int slice = bid & 3, bh = bid >> 2;
    int hh = bh % NHEADS, b = bh / NHEADS;
    int e0 = slice * 1024 + threadIdx.x * 4;
    bf16x4 loc[NCHUNK];
    float dec[NCHUNK];
    #pragma unroll
    for (int c = 0; c < NCHUNK; c++) {
        loc[c] = *(const bf16x4*)&states[(size_t)((b*NCHUNK+c)*NHEADS+hh)*4096 + e0];
        dec[c] = expf(Acs_g[((b*NHEADS+hh)*NCHUNK + c)*64 + 63]);
    }
    float S0 = 0.f, S1 = 0.f, S2 = 0.f, S3 = 0.f;
    #pragma unroll
    for (int c = 0; c < NCHUNK; c++) {
        bf16x4 l = loc[c];
        bf16x4 o; o[0] = (bf16)S0; o[1] = (bf16)S1; o[2] = (bf16)S2; o[3] = (bf16)S3;
        *(bf16x4*)&states[(size_t)((b*NCHUNK+c)*NHEADS+hh)*4096 + e0] = o;
        S0 = dec[c]*S0 + (float)l[0];
        S1 = dec[c]*S1 + (float)l[1];
        S2 = dec[c]*S2 + (float)l[2];
        S3 = dec[c]*S3 + (float)l[3];
    }
}

// --------------------------------- SSD: Y = Y_diag + Y_off + D*X (MFMA) -> bf16
__global__ __launch_bounds__(256) void ssd_out_kernel(
    const bf16* __restrict__ xs, const bf16* __restrict__ Bm,
    const bf16* __restrict__ Cm, const float* __restrict__ dtb,
    const bf16* __restrict__ states, const float* __restrict__ Acs_g,
    const float* __restrict__ Dv, bf16* __restrict__ Y) {
    int blk = blockIdx.x;
    int hh = blk % NHEADS;
    int bc = blk / NHEADS;
    int c = bc % NCHUNK, b = bc / NCHUNK;
    __shared__ __align__(16) bf16 sC [64 * SP];   // [l][n]
    __shared__ __align__(16) bf16 sBG[64 * SP];   // B[s][n] -> G'[l][s]
    __shared__ __align__(16) bf16 sXS[64 * SP];   // X^T[p][l] -> S[p][n]
    __shared__ float acs[64], dts[64];
    int t = threadIdx.x;
    bf16x8 sreg0, sreg1;                          // T14: S prefetch to regs
    {
        const bf16* sp = states + (size_t)blk * 4096 + t * 16;
        sreg0 = *(const bf16x8*)&sp[0];
        sreg1 = *(const bf16x8*)&sp[8];
    }
    if (t < 64) {
        acs[t] = Acs_g[((b * NHEADS + hh) * NCHUNK + c) * 64 + t];
        dts[t] = dtb[(b * SEQ + c * 64 + t) * NHEADS + hh];
    }
    {   // stage C, B natural; X transposed (raw)
        int l = t >> 2, c0 = (t & 3) * 16;
        int row = b * SEQ + c * 64 + l;
        *(bf16x8*)&sC[l * SP + c0]      = *(const bf16x8*)&Cm[(size_t)row * DSTATE + c0];
        *(bf16x8*)&sC[l * SP + c0 + 8]  = *(const bf16x8*)&Cm[(size_t)row * DSTATE + c0 + 8];
        *(bf16x8*)&sBG[l * SP + c0]     = *(const bf16x8*)&Bm[(size_t)row * DSTATE + c0];
        *(bf16x8*)&sBG[l * SP + c0 + 8] = *(const bf16x8*)&Bm[(size_t)row * DSTATE + c0 + 8];
        bf16x8 xv0 = *(const bf16x8*)&xs[(size_t)row * DINNER + hh * 64 + c0];
        bf16x8 xv1 = *(const bf16x8*)&xs[(size_t)row * DINNER + hh * 64 + c0 + 8];
        #pragma unroll
        for (int i = 0; i < 8; i++) {
            sXS[(c0 + i) * SP + l]     = xv0[i];
            sXS[(c0 + 8 + i) * SP + l] = xv1[i];
        }
    }
    __syncthreads();
    int lane = t & 63, w = t >> 6;
    int wm = w >> 1, wn = w & 1;
    int fr = lane & 15, fc = (lane >> 4) * 8;
    // ---- m1: G0 = C . B^T
    f32x4 g[2][2] = {};
    #pragma unroll
    for (int kk = 0; kk < 2; kk++) {
        bf16x8 a[2], bb[2];
        #pragma unroll
        for (int i = 0; i < 2; i++)
            a[i] = *(const bf16x8*)&sC[(wm * 32 + i * 16 + fr) * SP + kk * 32 + fc];
        #pragma unroll
        for (int j = 0; j < 2; j++)
            bb[j] = *(const bf16x8*)&sBG[(wn * 32 + j * 16 + fr) * SP + kk * 32 + fc];
        #pragma unroll
        for (int i = 0; i < 2; i++)
            #pragma unroll
            for (int j = 0; j < 2; j++)
                g[i][j] = __builtin_amdgcn_mfma_f32_16x16x32_bf16(a[i], bb[j], g[i][j], 0, 0, 0);
    }
    __syncthreads();           // all m1 reads of B done
    // ---- G' = tril(G0 * exp(acs_l - acs_s)) * dt_s
    #pragma unroll
    for (int i = 0; i < 2; i++) {
        #pragma unroll
        for (int j = 0; j < 2; j++) {
            int s = wn * 32 + j * 16 + (lane & 15);
            #pragma unroll
            for (int r = 0; r < 4; r++) {
                int l = wm * 32 + i * 16 + (lane >> 4) * 4 + r;
                float val = (s <= l) ? g[i][j][r] * expf(acs[l] - acs[s]) * dts[s] : 0.f;
                sBG[l * SP + s] = (bf16)val;
            }
        }
    }
    __syncthreads();           // G' visible
    // ---- m2: Y_diag = G' . X
    f32x4 yd[2][2] = {};
    #pragma unroll
    for (int kk = 0; kk < 2; kk++) {
        bf16x8 a[2], bb[2];
        #pragma unroll
        for (int i = 0; i < 2; i++)
            a[i] = *(const bf16x8*)&sBG[(wm * 32 + i * 16 + fr) * SP + kk * 32 + fc];
        #pragma unroll
        for (int j = 0; j < 2; j++)
            bb[j] = *(const bf16x8*)&sXS[(wn * 32 + j * 16 + fr) * SP + kk * 32 + fc];
        #pragma unroll
        for (int i = 0; i < 2; i++)
            #pragma unroll
            for (int j = 0; j < 2; j++)
                yd[i][j] = __builtin_amdgcn_mfma_f32_16x16x32_bf16(a[i], bb[j], yd[i][j], 0, 0, 0);
    }
    // raw X at output positions (D-skip), before sXS is overwritten
    float xk[2][2][4];
    #pragma unroll
    for (int i = 0; i < 2; i++)
        #pragma unroll
        for (int j = 0; j < 2; j++) {
            int p = wn * 32 + j * 16 + (lane & 15);
            #pragma unroll
            for (int r = 0; r < 4; r++) {
                int l = wm * 32 + i * 16 + (lane >> 4) * 4 + r;
                xk[i][j][r] = (float)sXS[p * SP + l];
            }
        }
    __syncthreads();           // all sXS (X^T) reads done
    {   // overwrite sXS with S_in [p][n]
        int p = t >> 2, n0 = (t & 3) * 16;
        *(bf16x8*)&sXS[p * SP + n0]     = sreg0;
        *(bf16x8*)&sXS[p * SP + n0 + 8] = sreg1;
    }
    __syncthreads();
    // ---- m3: Y_off = C . S^T
    f32x4 yo[2][2] = {};
    #pragma unroll
    for (int kk = 0; kk < 2; kk++) {
        bf16x8 a[2], bb[2];
        #pragma unroll
        for (int i = 0; i < 2; i++)
            a[i] = *(const bf16x8*)&sC[(wm * 32 + i * 16 + fr) * SP + kk * 32 + fc];
        #pragma unroll
        for (int j = 0; j < 2; j++)
            bb[j] = *(const bf16x8*)&sXS[(wn * 32 + j * 16 + fr) * SP + kk * 32 + fc];
        #pragma unroll
        for (int i = 0; i < 2; i++)
            #pragma unroll
            for (int j = 0; j < 2; j++)
                yo[i][j] = __builtin_amdgcn_mfma_f32_16x16x32_bf16(a[i], bb[j], yo[i][j], 0, 0, 0);
    }
    float Dh = Dv[hh];
    #pragma unroll
    for (int i = 0; i < 2; i++) {
        #pragma unroll
        for (int j = 0; j < 2; j++) {
            int p = wn * 32 + j * 16 + (lane & 15);
            #pragma unroll
            for (int r = 0; r < 4; r++) {
                int l = wm * 32 + i * 16 + (lane >> 4) * 4 + r;
                int row = b * SEQ + c * 64 + l;
                Y[(size_t)row * DINNER + hh * 64 + p] =
                    (bf16)(yd[i][j][r] + expf(acs[l]) * yo[i][j][r] + Dh * xk[i][j][r]);
            }
        }
    }
}

// --------------------------------------------------- gated RMSNorm -> bf16 (vec)
__global__ __launch_bounds__(256) void rms_kernel(
    const bf16* __restrict__ Y, const bf16* __restrict__ zx,
    const float* __restrict__ nw, bf16* __restrict__ yn) {
    int row = blockIdx.x;
    const bf16* yr = Y + (size_t)row * DINNER;
    const bf16* zr = zx + (size_t)row * NPAD;       // z = cols [0, 2048)
    bf16* outr = yn + (size_t)row * DINNER;
    int t = threadIdx.x;
    bf16x8 yv = *(const bf16x8*)&yr[t * 8];
    bf16x8 zv = *(const bf16x8*)&zr[t * 8];
    float vals[8];
    float ss = 0.f;
    #pragma unroll
    for (int i = 0; i < 8; i++) {
        float z = (float)zv[i];
        float v = (float)yv[i] * (z / (1.f + expf(-z)));
        vals[i] = v;
        ss += v * v;
    }
    for (int o = 32; o > 0; o >>= 1) ss += __shfl_down(ss, o);
    __shared__ float red[4];
    int wid = t >> 6, lane = t & 63;
    if (lane == 0) red[wid] = ss;
    __syncthreads();
    if (t == 0) { float a = 0; for (int i = 0; i < 4; i++) a += red[i]; red[0] = a; }
    __syncthreads();
    float r = rsqrtf(red[0] * (1.f / DINNER) + EPSF);
    float4 w0 = *(const float4*)&nw[t * 8];
    float4 w1 = *(const float4*)&nw[t * 8 + 4];
    bf16x8 o;
    const float* wp0 = (const float*)&w0;
    const float* wp1 = (const float*)&w1;
    #pragma unroll
    for (int i = 0; i < 8; i++)
        o[i] = (bf16)(vals[i] * r * ((i < 4) ? wp0[i] : wp1[i - 4]));
    *(bf16x8*)&outr[t * 8] = o;
}

// ---------------------------------------------------------------------------
extern "C" void kernel_launch(void* const* d_in, const int* in_sizes, int n_in,
                              void* d_out, int out_size, void* d_ws, size_t ws_size,
                              hipStream_t stream) {
    const float* x          = (const float*)d_in[0];
    const float* ln_w       = (const float*)d_in[1];
    const float* ln_b       = (const float*)d_in[2];
    const float* in_proj_w  = (const float*)d_in[3];
    const float* conv_w     = (const float*)d_in[4];
    const float* conv_b     = (const float*)d_in[5];
    const float* dt_bias    = (const float*)d_in[6];
    const float* A_log      = (const float*)d_in[7];
    const float* Dv         = (const float*)d_in[8];
    const float* norm_w     = (const float*)d_in[9];
    const float* out_proj_w = (const float*)d_in[10];
    float* out = (float*)d_out;

    char* ws = (char*)d_ws;
    size_t off = 0;
    auto alloc = [&](size_t bytes) { char* p = ws + off; off += (bytes + 255) & ~(size_t)255; return p; };
    bf16*  h_bf  = (bf16*) alloc((size_t)4096 * DMODEL * 2);     //  8.4 MB
    bf16*  zx    = (bf16*) alloc((size_t)4096 * NPAD * 2);       // 35.6 MB
    bf16*  xs    = (bf16*) alloc((size_t)4096 * DINNER * 2);     // 16.8 MB
    bf16*  states= (bf16*) alloc((size_t)2048 * 4096 * 2);       // 16.8 MB
    bf16*  Yb    = (bf16*) alloc((size_t)4096 * DINNER * 2);     // 16.8 MB
    bf16*  Bt1   = (bf16*) alloc((size_t)NPAD * DMODEL * 2);     //  8.9 MB
    bf16*  Bt2   = (bf16*) alloc((size_t)DMODEL * DINNER * 2);   //  4.2 MB
    float* dtb   = (float*)alloc((size_t)4096 * NHEADS * 4);     //  0.5 MB
    float* Acs   = (float*)alloc((size_t)2 * NHEADS * NCHUNK * 64 * 4);
    bf16* Bm = h_bf;                          // h_bf dead after GEMM1
    bf16* Cm = h_bf + (size_t)4096 * DSTATE;
    bf16* yn = xs;                            // xs dead after ssd_out

    // weight transposes + LayerNorm, one launch
    pre_kernel<<<6400 + 4096, 256, 0, stream>>>(
        x, ln_w, ln_b, h_bf, in_proj_w, out_proj_w, Bt1, Bt2);

    {   // zx = h @ in_proj_w   (bf16 out); 128x128 tiles, m-fast grid
        dim3 g((BATCH * SEQ) / 128, NPAD / 128);
        gemm_bf16_pipe3<128, 128, bf16><<<g, 256, 0, stream>>>(
            h_bf, Bt1, zx, BATCH * SEQ, NPAD, DMODEL, nullptr);
    }

    convdt_kernel<<<(BATCH * SEQ * NG) / 256, 256, 0, stream>>>(
        zx, conv_w, conv_b, dt_bias, xs, Bm, Cm, dtb);

    ssd_states_kernel<<<BATCH * NCHUNK * NHEADS, 256, 0, stream>>>(
        xs, Bm, dtb, A_log, states, Acs);

    ssd_scan_kernel<<<BATCH * NHEADS * 4, 256, 0, stream>>>(states, Acs);

    ssd_out_kernel<<<BATCH * NCHUNK * NHEADS, 256, 0, stream>>>(
        xs, Bm, Cm, dtb, states, Acs, Dv, Yb);

    rms_kernel<<<BATCH * SEQ, 256, 0, stream>>>(Yb, zx, norm_w, yn);

    {   // out = yn @ out_proj_w + x; 128x64 tiles, m-fast grid (512 blocks)
        dim3 g((BATCH * SEQ) / 128, DMODEL / 64);
        gemm_bf16_pipe3<128, 64, float><<<g, 256, 0, stream>>>(
            yn, Bt2, out, BATCH * SEQ, DMODEL, DINNER, x);
    }
}

// Round 12
// 194.802 us; speedup vs baseline: 1.2506x; 1.0055x over previous
//
#include <hip/hip_runtime.h>
#include <hip/hip_bf16.h>

#define BATCH   2
#define SEQ     2048
#define DMODEL  1024
#define DINNER  2048
#define DSTATE  64
#define NHEADS  32
#define HEADDIM 64
#define CONVDIM 2176
#define DINPROJ 4256
#define NPAD    4352        // DINPROJ padded to 34*128 for the MFMA GEMM
#define NCHUNK  32          // SEQ / 64
#define EPSF    1e-5f
#define SP      88          // LDS row stride (bf16) for SSD kernels
#define NG      276         // (CONVDIM + NHEADS) / 8 channel-groups per row

typedef __bf16 bf16;
typedef bf16  bf16x4 __attribute__((ext_vector_type(4)));
typedef bf16  bf16x8 __attribute__((ext_vector_type(8)));
typedef float f32x4  __attribute__((ext_vector_type(4)));

template<int V> struct IC { static constexpr int value = V; };

__device__ __forceinline__ void gll16(const bf16* g, bf16* l) {
    __builtin_amdgcn_global_load_lds(
        (const __attribute__((address_space(1))) void*)g,
        (__attribute__((address_space(3))) void*)l, 16, 0, 0);
}

template<int VM> __device__ __forceinline__ void vmwait() {
    if constexpr (VM == 0)  asm volatile("s_waitcnt vmcnt(0)" ::: "memory");
    if constexpr (VM == 4)  asm volatile("s_waitcnt vmcnt(4)" ::: "memory");
    if constexpr (VM == 6)  asm volatile("s_waitcnt vmcnt(6)" ::: "memory");
    if constexpr (VM == 8)  asm volatile("s_waitcnt vmcnt(8)" ::: "memory");
    if constexpr (VM == 12) asm volatile("s_waitcnt vmcnt(12)" ::: "memory");
}

// ------------- preprocessing: weight transposes (+bf16) AND LayerNorm, one launch
__global__ __launch_bounds__(256) void pre_kernel(
    const float* __restrict__ x, const float* __restrict__ lw,
    const float* __restrict__ lb, bf16* __restrict__ h,
    const float* __restrict__ W1, const float* __restrict__ W2,
    bf16* __restrict__ Bt1, bf16* __restrict__ Bt2) {
    __shared__ float sm[32][33];
    int bid = blockIdx.x;
    int t = threadIdx.x;
    if (bid < 6400) {            // weight transpose path
        const float* W; bf16* Bt; int K, N, NP, bx, by;
        if (bid < 4352) {        // W1: 136 x 32 tile-grid
            W = W1; Bt = Bt1; K = 1024; N = 4256; NP = 4352;
            bx = bid % 136; by = bid / 136;
        } else {                 // W2: 32 x 64 tile-grid
            int b2 = bid - 4352;
            W = W2; Bt = Bt2; K = 2048; N = 1024; NP = 1024;
            bx = b2 % 32; by = b2 / 32;
        }
        int n0 = bx * 32, k0 = by * 32;
        int tx = t & 31, ty = t >> 5;   // 32 x 8 staging (coalesced fp32 reads)
        for (int i = 0; i < 4; i++) {
            int k = k0 + ty + i * 8, n = n0 + tx;
            sm[ty + i * 8][tx] = (n < N) ? W[(size_t)k * N + n] : 0.f;
        }
        __syncthreads();
        int nl = t >> 3, kg = (t & 7) * 4;
        int n = n0 + nl;
        if (n < NP) {
            bf16x4 v;
            #pragma unroll
            for (int j = 0; j < 4; j++) v[j] = (bf16)sm[kg + j][nl];
            *(bf16x4*)&Bt[(size_t)n * K + k0 + kg] = v;
        }
        return;
    }
    // LayerNorm path
    int row = bid - 6400;
    const float* xr = x + (size_t)row * DMODEL;
    bf16* hr = h + (size_t)row * DMODEL;
    float4 v = ((const float4*)xr)[t];
    float s  = v.x + v.y + v.z + v.w;
    float ss = v.x*v.x + v.y*v.y + v.z*v.z + v.w*v.w;
    for (int o = 32; o > 0; o >>= 1) { s += __shfl_down(s, o); ss += __shfl_down(ss, o); }
    int wid = t >> 6, lane = t & 63;
    if (lane == 0) { sm[0][wid] = s; sm[1][wid] = ss; }
    __syncthreads();
    if (t == 0) {
        float a = 0, b2 = 0;
        for (int i = 0; i < 4; i++) { a += sm[0][i]; b2 += sm[1][i]; }
        sm[0][0] = a; sm[1][0] = b2;
    }
    __syncthreads();
    float mean = sm[0][0] * (1.f / DMODEL);
    float var  = sm[1][0] * (1.f / DMODEL) - mean * mean;
    float rstd = rsqrtf(var + EPSF);
    float4 wv = ((const float4*)lw)[t];
    float4 bv = ((const float4*)lb)[t];
    bf16x4 o;
    o[0] = (bf16)((v.x - mean) * rstd * wv.x + bv.x);
    o[1] = (bf16)((v.y - mean) * rstd * wv.y + bv.y);
    o[2] = (bf16)((v.z - mean) * rstd * wv.z + bv.z);
    o[3] = (bf16)((v.w - mean) * rstd * wv.w + bv.w);
    *(bf16x4*)&hr[t * 4] = o;
}

// ---------------- bf16 MFMA GEMM, 3-deep ring pipeline (T4 counted vmcnt)
// 1D grid with XCD-aware swizzle (T1): XCD k owns a (mt/8)-m-tile strip for all
// n -> its A strip (~1 MB) stays L2-resident; converts HBM-latency misses into
// L2 hits that fit the 3-ring's latency budget.
template<int BM, int BN, typename OUT_T>
__global__ __launch_bounds__(256) void gemm_bf16_pipe3(
    const bf16* __restrict__ A, const bf16* __restrict__ Bt,
    OUT_T* __restrict__ C, int M, int N, int K,
    const float* __restrict__ resid) {
    constexpr int MR = BM / 32;
    constexpr int NR = BN / 32;
    constexpr int LPT = BM / 64 + BN / 64;   // gll16 per thread per tile
    __shared__ __align__(16) bf16 sA[3][BM * 32];
    __shared__ __align__(16) bf16 sB[3][BN * 32];
    int t = threadIdx.x;
    int lane = t & 63, w = t >> 6;
    // XCD swizzle: bijective when (M/BM) % 8 == 0 (holds: 4096/128 = 32)
    int mt = M / BM;
    int strip = mt >> 3;
    int bid = blockIdx.x;
    int xcd = bid & 7, idx = bid >> 3;
    int m0 = (xcd * strip + (idx % strip)) * BM;
    int n0 = (idx / strip) * BN;
    int wm = w >> 1, wn = w & 1;
    f32x4 acc[MR][NR] = {};
    int srow = w * 16 + (lane >> 2);
    int scol = (lane & 3) * 8;
    int fr = lane & 15;
    int fc = (lane >> 4) * 8;
    auto stage = [&](int buf, int k0) {
        #pragma unroll
        for (int i = 0; i < BM / 64; i++)
            gll16(&A[(size_t)(m0 + i * 64 + srow) * K + k0 + scol],
                  &sA[buf][(i * 64 + w * 16) * 32]);
        #pragma unroll
        for (int i = 0; i < BN / 64; i++)
            gll16(&Bt[(size_t)(n0 + i * 64 + srow) * K + k0 + scol],
                  &sB[buf][(i * 64 + w * 16) * 32]);
    };
    int nt = K / 32;
    stage(0, 0); stage(1, 32); stage(2, 64);     // 3 tiles in flight
    int tt = 0;
    auto iter = [&](auto vmtag) {
        constexpr int VM = decltype(vmtag)::value;
        vmwait<VM>();                            // own tile-tt loads landed
        __builtin_amdgcn_s_barrier();            // ...for ALL waves -> buf ready
        int buf = tt % 3;
        bf16x8 af[MR], bfr[NR];
        #pragma unroll
        for (int i = 0; i < MR; i++)
            af[i] = *(const bf16x8*)&sA[buf][(wm * (BM/2) + i * 16 + fr) * 32 + fc];
        #pragma unroll
        for (int j = 0; j < NR; j++)
            bfr[j] = *(const bf16x8*)&sB[buf][(wn * (BN/2) + j * 16 + fr) * 32 + fc];
        asm volatile("s_waitcnt lgkmcnt(0)" ::: "memory");   // reads returned
        __builtin_amdgcn_sched_barrier(0);
        __builtin_amdgcn_s_barrier();            // all waves done reading buf
        if (tt + 3 < nt) stage(buf, (tt + 3) * 32);          // reuse ring slot
        #pragma unroll
        for (int i = 0; i < MR; i++)
            #pragma unroll
            for (int j = 0; j < NR; j++)
                acc[i][j] = __builtin_amdgcn_mfma_f32_16x16x32_bf16(
                    af[i], bfr[j], acc[i][j], 0, 0, 0);
        tt++;
    };
    for (; tt < nt - 2; ) iter(IC<2 * LPT>{});
    iter(IC<LPT>{});
    iter(IC<0>{});
    #pragma unroll
    for (int i = 0; i < MR; i++) {
        #pragma unroll
        for (int j = 0; j < NR; j++) {
            int col = n0 + wn * (BN/2) + j * 16 + (lane & 15);
            #pragma unroll
            for (int r = 0; r < 4; r++) {
                int row = m0 + wm * (BM/2) + i * 16 + (lane >> 4) * 4 + r;
                float v = acc[i][j][r];
                if (resid) v += resid[(size_t)row * N + col];
                C[(size_t)row * N + col] = (OUT_T)v;
            }
        }
    }
}

// --------- causal depthwise conv + SiLU + dt softplus, VECTORIZED (8 ch/thread)
__global__ __launch_bounds__(256) void convdt_kernel(
    const bf16* __restrict__ zx, const float* __restrict__ cw,
    const float* __restrict__ cb, const float* __restrict__ dt_bias,
    bf16* __restrict__ xs, bf16* __restrict__ Bm, bf16* __restrict__ Cm,
    float* __restrict__ dtb) {
    int idx = blockIdx.x * 256 + threadIdx.x;        // 4096 * NG
    int g = idx % NG;
    int bl = idx / NG;
    int b = bl / SEQ, tt = bl % SEQ;
    const bf16* zrow = zx + (size_t)(b * SEQ) * NPAD + DINNER;
    if (g >= 272) {                                  // dt path: 8 heads
        int hh0 = (g - 272) * 8;
        bf16x8 v = *(const bf16x8*)&zx[(size_t)bl * NPAD + DINNER + CONVDIM + hh0];
        float4 o0, o1;
        #pragma unroll
        for (int i = 0; i < 8; i++) {
            float u = (float)v[i] + dt_bias[hh0 + i];
            ((i < 4) ? ((float*)&o0) : ((float*)&o1))[i & 3] =
                (u > 20.f) ? u : log1pf(expf(u));
        }
        *(float4*)&dtb[bl * NHEADS + hh0]     = o0;
        *(float4*)&dtb[bl * NHEADS + hh0 + 4] = o1;
        return;
    }
    int ch0 = g * 8;
    float acc[8];
    {
        float4 c0 = *(const float4*)&cb[ch0];
        float4 c1 = *(const float4*)&cb[ch0 + 4];
        acc[0]=c0.x; acc[1]=c0.y; acc[2]=c0.z; acc[3]=c0.w;
        acc[4]=c1.x; acc[5]=c1.y; acc[6]=c1.z; acc[7]=c1.w;
    }
    float4 cwv[8];                                   // cw[ch][4], 8 channels
    #pragma unroll
    for (int i = 0; i < 8; i++) cwv[i] = *(const float4*)&cw[(ch0 + i) * 4];
    #pragma unroll
    for (int k = 0; k < 4; k++) {
        int tp = tt - 3 + k;
        if (tp >= 0) {
            bf16x8 v = *(const bf16x8*)&zrow[(size_t)tp * NPAD + ch0];
            #pragma unroll
            for (int i = 0; i < 8; i++)
                acc[i] += (float)v[i] * ((const float*)&cwv[i])[k];
        }
    }
    bf16x8 o;
    #pragma unroll
    for (int i = 0; i < 8; i++) {
        float s = acc[i] / (1.f + expf(-acc[i]));
        o[i] = (bf16)s;
    }
    if (ch0 < DINNER)              *(bf16x8*)&xs[(size_t)bl * DINNER + ch0] = o;
    else if (ch0 < DINNER+DSTATE)  *(bf16x8*)&Bm[bl * DSTATE + (ch0 - DINNER)] = o;
    else                           *(bf16x8*)&Cm[bl * DSTATE + (ch0 - DINNER - DSTATE)] = o;
}

// ----------------------------------------- SSD: per-chunk local states (MFMA)
__global__ __launch_bounds__(256) void ssd_states_kernel(
    const bf16* __restrict__ xs, const bf16* __restrict__ Bm,
    const float* __restrict__ dtb, const float* __restrict__ A_log,
    bf16* __restrict__ states, float* __restrict__ Acs_g) {
    int blk = blockIdx.x;
    int hh = blk % NHEADS;
    int bc = blk / NHEADS;
    int c = bc % NCHUNK, b = bc / NCHUNK;
    __shared__ __align__(16) bf16 sXT[64 * SP];   // [p][l]
    __shared__ __align__(16) bf16 sBT[64 * SP];   // [n][l]
    __shared__ float dts[64], acs[64];
    int t = threadIdx.x;
    float Ah = -expf(A_log[hh]);
    if (t < 64) {                                // wave 0: load + parallel scan
        float dv = dtb[(b * SEQ + c * 64 + t) * NHEADS + hh];
        float v = dv * Ah;
        #pragma unroll
        for (int o = 1; o < 64; o <<= 1) {
            float p = __shfl_up(v, o);
            if (t >= o) v += p;
        }
        dts[t] = dv; acs[t] = v;
        Acs_g[((b * NHEADS + hh) * NCHUNK + c) * 64 + t] = v;
    }
    __syncthreads();
    float alast = acs[63];
    {   // stage transposed, weighted
        int l = t >> 2, c0 = (t & 3) * 16;
        int row = b * SEQ + c * 64 + l;
        float dl = dts[l];
        float wl = expf(alast - acs[l]);
        bf16x8 xv0 = *(const bf16x8*)&xs[(size_t)row * DINNER + hh * 64 + c0];
        bf16x8 xv1 = *(const bf16x8*)&xs[(size_t)row * DINNER + hh * 64 + c0 + 8];
        bf16x8 bv0 = *(const bf16x8*)&Bm[(size_t)row * DSTATE + c0];
        bf16x8 bv1 = *(const bf16x8*)&Bm[(size_t)row * DSTATE + c0 + 8];
        #pragma unroll
        for (int i = 0; i < 8; i++) {
            sXT[(c0 + i) * SP + l]     = (bf16)((float)xv0[i] * dl);
            sXT[(c0 + 8 + i) * SP + l] = (bf16)((float)xv1[i] * dl);
            sBT[(c0 + i) * SP + l]     = (bf16)((float)bv0[i] * wl);
            sBT[(c0 + 8 + i) * SP + l] = (bf16)((float)bv1[i] * wl);
        }
    }
    __syncthreads();
    int lane = t & 63, w = t >> 6;
    int wm = w >> 1, wn = w & 1;
    int fr = lane & 15, fc = (lane >> 4) * 8;
    f32x4 acc[2][2] = {};
    #pragma unroll
    for (int kk = 0; kk < 2; kk++) {
        bf16x8 a[2], bb[2];
        #pragma unroll
        for (int i = 0; i < 2; i++)
            a[i] = *(const bf16x8*)&sXT[(wm * 32 + i * 16 + fr) * SP + kk * 32 + fc];
        #pragma unroll
        for (int j = 0; j < 2; j++)
            bb[j] = *(const bf16x8*)&sBT[(wn * 32 + j * 16 + fr) * SP + kk * 32 + fc];
        #pragma unroll
        for (int i = 0; i < 2; i++)
            #pragma unroll
            for (int j = 0; j < 2; j++)
                acc[i][j] = __builtin_amdgcn_mfma_f32_16x16x32_bf16(
                    a[i], bb[j], acc[i][j], 0, 0, 0);
    }
    bf16* outp = states + (size_t)blk * 4096;
    #pragma unroll
    for (int i = 0; i < 2; i++)
        #pragma unroll
        for (int j = 0; j < 2; j++)
            #pragma unroll
            for (int r = 0; r < 4; r++)
                outp[(wm*32 + i*16 + (lane>>4)*4 + r) * 64 + wn*32 + j*16 + (lane&15)]
                    = (bf16)acc[i][j][r];
}

// ------------------------------------------- SSD: inter-chunk sequential scan
__global__ __launch_bounds__(256) void ssd_scan_kernel(
    bf16* __restrict__ states, const float* __restrict__ Acs_g) {
    int bid = blockIdx.x;
    int slice = bid & 3, bh = bid >> 2;
    int hh = bh % NHEADS, b = bh / NHEADS;
    int e0 = slice * 1024 + threadIdx.x * 4;
    bf16x4 loc[NCHUNK];
    float dec[NCHUNK];
    #pragma unroll
    for (int c = 0; c < NCHUNK; c++) {
        loc[c] = *(const bf16x4*)&states[(size_t)((b*NCHUNK+c)*NHEADS+hh)*4096 + e0];
        dec[c] = expf(Acs_g[((b*NHEADS+hh)*NCHUNK + c)*64 + 63]);
    }
    float S0 = 0.f, S1 = 0.f, S2 = 0.f, S3 = 0.f;
    #pragma unroll
    for (int c = 0; c < NCHUNK; c++) {
        bf16x4 l = loc[c];
        bf16x4 o; o[0] = (bf16)S0; o[1] = (bf16)S1; o[2] = (bf16)S2; o[3] = (bf16)S3;
        *(bf16x4*)&states[(size_t)((b*NCHUNK+c)*NHEADS+hh)*4096 + e0] = o;
        S0 = dec[c]*S0 + (float)l[0];
        S1 = dec[c]*S1 + (float)l[1];
        S2 = dec[c]*S2 + (float)l[2];
        S3 = dec[c]*S3 + (float)l[3];
    }
}

// --------------------------------- SSD: Y = Y_diag + Y_off + D*X (MFMA) -> bf16
__global__ __launch_bounds__(256) void ssd_out_kernel(
    const bf16* __restrict__ xs, const bf16* __restrict__ Bm,
    const bf16* __restrict__ Cm, const float* __restrict__ dtb,
    const bf16* __restrict__ states, const float* __restrict__ Acs_g,
    const float* __restrict__ Dv, bf16* __restrict__ Y) {
    int blk = blockIdx.x;
    int hh = blk % NHEADS;
    int bc = blk / NHEADS;
    int c = bc % NCHUNK, b = bc / NCHUNK;
    __shared__ __align__(16) bf16 sC [64 * SP];   // [l][n]
    __shared__ __align__(16) bf16 sBG[64 * SP];   // B[s][n] -> G'[l][s]
    __shared__ __align__(16) bf16 sXS[64 * SP];   // X^T[p][l] -> S[p][n]
    __shared__ float acs[64], dts[64];
    int t = threadIdx.x;
    bf16x8 sreg0, sreg1;                          // T14: S prefetch to regs
    {
        const bf16* sp = states + (size_t)blk * 4096 + t * 16;
        sreg0 = *(const bf16x8*)&sp[0];
        sreg1 = *(const bf16x8*)&sp[8];
    }
    if (t < 64) {
        acs[t] = Acs_g[((b * NHEADS + hh) * NCHUNK + c) * 64 + t];
        dts[t] = dtb[(b * SEQ + c * 64 + t) * NHEADS + hh];
    }
    {   // stage C, B natural; X transposed (raw)
        int l = t >> 2, c0 = (t & 3) * 16;
        int row = b * SEQ + c * 64 + l;
        *(bf16x8*)&sC[l * SP + c0]      = *(const bf16x8*)&Cm[(size_t)row * DSTATE + c0];
        *(bf16x8*)&sC[l * SP + c0 + 8]  = *(const bf16x8*)&Cm[(size_t)row * DSTATE + c0 + 8];
        *(bf16x8*)&sBG[l * SP + c0]     = *(const bf16x8*)&Bm[(size_t)row * DSTATE + c0];
        *(bf16x8*)&sBG[l * SP + c0 + 8] = *(const bf16x8*)&Bm[(size_t)row * DSTATE + c0 + 8];
        bf16x8 xv0 = *(const bf16x8*)&xs[(size_t)row * DINNER + hh * 64 + c0];
        bf16x8 xv1 = *(const bf16x8*)&xs[(size_t)row * DINNER + hh * 64 + c0 + 8];
        #pragma unroll
        for (int i = 0; i < 8; i++) {
            sXS[(c0 + i) * SP + l]     = xv0[i];
            sXS[(c0 + 8 + i) * SP + l] = xv1[i];
        }
    }
    __syncthreads();
    int lane = t & 63, w = t >> 6;
    int wm = w >> 1, wn = w & 1;
    int fr = lane & 15, fc = (lane >> 4) * 8;
    // ---- m1: G0 = C . B^T
    f32x4 g[2][2] = {};
    #pragma unroll
    for (int kk = 0; kk < 2; kk++) {
        bf16x8 a[2], bb[2];
        #pragma unroll
        for (int i = 0; i < 2; i++)
            a[i] = *(const bf16x8*)&sC[(wm * 32 + i * 16 + fr) * SP + kk * 32 + fc];
        #pragma unroll
        for (int j = 0; j < 2; j++)
            bb[j] = *(const bf16x8*)&sBG[(wn * 32 + j * 16 + fr) * SP + kk * 32 + fc];
        #pragma unroll
        for (int i = 0; i < 2; i++)
            #pragma unroll
            for (int j = 0; j < 2; j++)
                g[i][j] = __builtin_amdgcn_mfma_f32_16x16x32_bf16(a[i], bb[j], g[i][j], 0, 0, 0);
    }
    __syncthreads();           // all m1 reads of B done
    // ---- G' = tril(G0 * exp(acs_l - acs_s)) * dt_s
    #pragma unroll
    for (int i = 0; i < 2; i++) {
        #pragma unroll
        for (int j = 0; j < 2; j++) {
            int s = wn * 32 + j * 16 + (lane & 15);
            #pragma unroll
            for (int r = 0; r < 4; r++) {
                int l = wm * 32 + i * 16 + (lane >> 4) * 4 + r;
                float val = (s <= l) ? g[i][j][r] * expf(acs[l] - acs[s]) * dts[s] : 0.f;
                sBG[l * SP + s] = (bf16)val;
            }
        }
    }
    __syncthreads();           // G' visible
    // ---- m2: Y_diag = G' . X
    f32x4 yd[2][2] = {};
    #pragma unroll
    for (int kk = 0; kk < 2; kk++) {
        bf16x8 a[2], bb[2];
        #pragma unroll
        for (int i = 0; i < 2; i++)
            a[i] = *(const bf16x8*)&sBG[(wm * 32 + i * 16 + fr) * SP + kk * 32 + fc];
        #pragma unroll
        for (int j = 0; j < 2; j++)
            bb[j] = *(const bf16x8*)&sXS[(wn * 32 + j * 16 + fr) * SP + kk * 32 + fc];
        #pragma unroll
        for (int i = 0; i < 2; i++)
            #pragma unroll
            for (int j = 0; j < 2; j++)
                yd[i][j] = __builtin_amdgcn_mfma_f32_16x16x32_bf16(a[i], bb[j], yd[i][j], 0, 0, 0);
    }
    // raw X at output positions (D-skip), before sXS is overwritten
    float xk[2][2][4];
    #pragma unroll
    for (int i = 0; i < 2; i++)
        #pragma unroll
        for (int j = 0; j < 2; j++) {
            int p = wn * 32 + j * 16 + (lane & 15);
            #pragma unroll
            for (int r = 0; r < 4; r++) {
                int l = wm * 32 + i * 16 + (lane >> 4) * 4 + r;
                xk[i][j][r] = (float)sXS[p * SP + l];
            }
        }
    __syncthreads();           // all sXS (X^T) reads done
    {   // overwrite sXS with S_in [p][n]
        int p = t >> 2, n0 = (t & 3) * 16;
        *(bf16x8*)&sXS[p * SP + n0]     = sreg0;
        *(bf16x8*)&sXS[p * SP + n0 + 8] = sreg1;
    }
    __syncthreads();
    // ---- m3: Y_off = C . S^T
    f32x4 yo[2][2] = {};
    #pragma unroll
    for (int kk = 0; kk < 2; kk++) {
        bf16x8 a[2], bb[2];
        #pragma unroll
        for (int i = 0; i < 2; i++)
            a[i] = *(const bf16x8*)&sC[(wm * 32 + i * 16 + fr) * SP + kk * 32 + fc];
        #pragma unroll
        for (int j = 0; j < 2; j++)
            bb[j] = *(const bf16x8*)&sXS[(wn * 32 + j * 16 + fr) * SP + kk * 32 + fc];
        #pragma unroll
        for (int i = 0; i < 2; i++)
            #pragma unroll
            for (int j = 0; j < 2; j++)
                yo[i][j] = __builtin_amdgcn_mfma_f32_16x16x32_bf16(a[i], bb[j], yo[i][j], 0, 0, 0);
    }
    float Dh = Dv[hh];
    #pragma unroll
    for (int i = 0; i < 2; i++) {
        #pragma unroll
        for (int j = 0; j < 2; j++) {
            int p = wn * 32 + j * 16 + (lane & 15);
            #pragma unroll
            for (int r = 0; r < 4; r++) {
                int l = wm * 32 + i * 16 + (lane >> 4) * 4 + r;
                int row = b * SEQ + c * 64 + l;
                Y[(size_t)row * DINNER + hh * 64 + p] =
                    (bf16)(yd[i][j][r] + expf(acs[l]) * yo[i][j][r] + Dh * xk[i][j][r]);
            }
        }
    }
}

// --------------------------------------------------- gated RMSNorm -> bf16 (vec)
__global__ __launch_bounds__(256) void rms_kernel(
    const bf16* __restrict__ Y, const bf16* __restrict__ zx,
    const float* __restrict__ nw, bf16* __restrict__ yn) {
    int row = blockIdx.x;
    const bf16* yr = Y + (size_t)row * DINNER;
    const bf16* zr = zx + (size_t)row * NPAD;       // z = cols [0, 2048)
    bf16* outr = yn + (size_t)row * DINNER;
    int t = threadIdx.x;
    bf16x8 yv = *(const bf16x8*)&yr[t * 8];
    bf16x8 zv = *(const bf16x8*)&zr[t * 8];
    float vals[8];
    float ss = 0.f;
    #pragma unroll
    for (int i = 0; i < 8; i++) {
        float z = (float)zv[i];
        float v = (float)yv[i] * (z / (1.f + expf(-z)));
        vals[i] = v;
        ss += v * v;
    }
    for (int o = 32; o > 0; o >>= 1) ss += __shfl_down(ss, o);
    __shared__ float red[4];
    int wid = t >> 6, lane = t & 63;
    if (lane == 0) red[wid] = ss;
    __syncthreads();
    if (t == 0) { float a = 0; for (int i = 0; i < 4; i++) a += red[i]; red[0] = a; }
    __syncthreads();
    float r = rsqrtf(red[0] * (1.f / DINNER) + EPSF);
    float4 w0 = *(const float4*)&nw[t * 8];
    float4 w1 = *(const float4*)&nw[t * 8 + 4];
    bf16x8 o;
    const float* wp0 = (const float*)&w0;
    const float* wp1 = (const float*)&w1;
    #pragma unroll
    for (int i = 0; i < 8; i++)
        o[i] = (bf16)(vals[i] * r * ((i < 4) ? wp0[i] : wp1[i - 4]));
    *(bf16x8*)&outr[t * 8] = o;
}

// ---------------------------------------------------------------------------
extern "C" void kernel_launch(void* const* d_in, const int* in_sizes, int n_in,
                              void* d_out, int out_size, void* d_ws, size_t ws_size,
                              hipStream_t stream) {
    const float* x          = (const float*)d_in[0];
    const float* ln_w       = (const float*)d_in[1];
    const float* ln_b       = (const float*)d_in[2];
    const float* in_proj_w  = (const float*)d_in[3];
    const float* conv_w     = (const float*)d_in[4];
    const float* conv_b     = (const float*)d_in[5];
    const float* dt_bias    = (const float*)d_in[6];
    const float* A_log      = (const float*)d_in[7];
    const float* Dv         = (const float*)d_in[8];
    const float* norm_w     = (const float*)d_in[9];
    const float* out_proj_w = (const float*)d_in[10];
    float* out = (float*)d_out;

    char* ws = (char*)d_ws;
    size_t off = 0;
    auto alloc = [&](size_t bytes) { char* p = ws + off; off += (bytes + 255) & ~(size_t)255; return p; };
    bf16*  h_bf  = (bf16*) alloc((size_t)4096 * DMODEL * 2);     //  8.4 MB
    bf16*  zx    = (bf16*) alloc((size_t)4096 * NPAD * 2);       // 35.6 MB
    bf16*  xs    = (bf16*) alloc((size_t)4096 * DINNER * 2);     // 16.8 MB
    bf16*  states= (bf16*) alloc((size_t)2048 * 4096 * 2);       // 16.8 MB
    bf16*  Yb    = (bf16*) alloc((size_t)4096 * DINNER * 2);     // 16.8 MB
    bf16*  Bt1   = (bf16*) alloc((size_t)NPAD * DMODEL * 2);     //  8.9 MB
    bf16*  Bt2   = (bf16*) alloc((size_t)DMODEL * DINNER * 2);   //  4.2 MB
    float* dtb   = (float*)alloc((size_t)4096 * NHEADS * 4);     //  0.5 MB
    float* Acs   = (float*)alloc((size_t)2 * NHEADS * NCHUNK * 64 * 4);
    bf16* Bm = h_bf;                          // h_bf dead after GEMM1
    bf16* Cm = h_bf + (size_t)4096 * DSTATE;
    bf16* yn = xs;                            // xs dead after ssd_out

    // weight transposes + LayerNorm, one launch
    pre_kernel<<<6400 + 4096, 256, 0, stream>>>(
        x, ln_w, ln_b, h_bf, in_proj_w, out_proj_w, Bt1, Bt2);

    {   // zx = h @ in_proj_w   (bf16 out); 128x128 tiles, XCD-swizzled 1D grid
        gemm_bf16_pipe3<128, 128, bf16><<<32 * 34, 256, 0, stream>>>(
            h_bf, Bt1, zx, BATCH * SEQ, NPAD, DMODEL, nullptr);
    }

    convdt_kernel<<<(BATCH * SEQ * NG) / 256, 256, 0, stream>>>(
        zx, conv_w, conv_b, dt_bias, xs, Bm, Cm, dtb);

    ssd_states_kernel<<<BATCH * NCHUNK * NHEADS, 256, 0, stream>>>(
        xs, Bm, dtb, A_log, states, Acs);

    ssd_scan_kernel<<<BATCH * NHEADS * 4, 256, 0, stream>>>(states, Acs);

    ssd_out_kernel<<<BATCH * NCHUNK * NHEADS, 256, 0, stream>>>(
        xs, Bm, Cm, dtb, states, Acs, Dv, Yb);

    rms_kernel<<<BATCH * SEQ, 256, 0, stream>>>(Yb, zx, norm_w, yn);

    {   // out = yn @ out_proj_w + x; 128x64 tiles, XCD-swizzled 1D grid
        gemm_bf16_pipe3<128, 64, float><<<32 * 16, 256, 0, stream>>>(
            yn, Bt2, out, BATCH * SEQ, DMODEL, DINNER, x);
    }
}